// Round 1
// baseline (4361.523 us; speedup 1.0000x reference)
//
#include <hip/hip_runtime.h>
#include <hip/hip_bf16.h>
#include <math.h>

#define TAU 0.5f

// ---------------------------------------------------------------------------
// Feature SpMM (COO): AX[row[e], :] += val[e] * X[col[e], :]
// 16 threads per edge, float4 per thread (D=64). Atomic scatter.
// ---------------------------------------------------------------------------
__global__ void spmm_feat_kernel(const int* __restrict__ row,
                                 const int* __restrict__ col,
                                 const float* __restrict__ val,
                                 const float* __restrict__ X,
                                 float* __restrict__ AX, int E) {
    int gid = blockIdx.x * 256 + threadIdx.x;
    int e = gid >> 4;
    int f = gid & 15;
    if (e >= E) return;
    int r = row[e];
    int c = col[e];
    float v = val[e];
    const float4* Xv = (const float4*)X;
    float4 x = Xv[c * 16 + f];
    float* out = AX + r * 64 + f * 4;
    atomicAdd(out + 0, v * x.x);
    atomicAdd(out + 1, v * x.y);
    atomicAdd(out + 2, v * x.z);
    atomicAdd(out + 3, v * x.w);
}

// ---------------------------------------------------------------------------
// X += relu(AX @ W^T).  W is (64,64) row-major; H[i,j] = sum_k AX[i,k]*W[j,k].
// W staged transposed in LDS (stride 65 to avoid bank conflicts).
// 16 nodes per block of 256 threads; each thread does 4 (node,col) pairs.
// ---------------------------------------------------------------------------
__global__ void layer_kernel(const float* __restrict__ AX,
                             const float* __restrict__ W,
                             float* __restrict__ X, int n) {
    __shared__ float Wt[64 * 65];
    __shared__ float AXs[16 * 64];
    int tid = threadIdx.x;
    for (int i = tid; i < 4096; i += 256) {
        int j = i >> 6, k = i & 63;
        Wt[k * 65 + j] = W[i];
    }
    int node0 = blockIdx.x * 16;
    for (int i = tid; i < 1024; i += 256) {
        int node = node0 + (i >> 6);
        AXs[i] = (node < n) ? AX[node * 64 + (i & 63)] : 0.f;
    }
    __syncthreads();
    int col = tid & 63;
    int nq = tid >> 6;  // 0..3
    float acc0 = 0.f, acc1 = 0.f, acc2 = 0.f, acc3 = 0.f;
    for (int k = 0; k < 64; ++k) {
        float w = Wt[k * 65 + col];
        acc0 += AXs[(nq + 0) * 64 + k] * w;
        acc1 += AXs[(nq + 4) * 64 + k] * w;
        acc2 += AXs[(nq + 8) * 64 + k] * w;
        acc3 += AXs[(nq + 12) * 64 + k] * w;
    }
    float accs[4] = {acc0, acc1, acc2, acc3};
#pragma unroll
    for (int j = 0; j < 4; ++j) {
        int node = node0 + nq + 4 * j;
        if (node < n) {
            int idx = node * 64 + col;
            X[idx] = X[idx] + fmaxf(accs[j], 0.f);
        }
    }
}

// ---------------------------------------------------------------------------
// s[i] = dot(X[i,:], Ws[0,:])  — wave-per-node shuffle reduction.
// ---------------------------------------------------------------------------
__global__ void score_kernel(const float* __restrict__ X,
                             const float* __restrict__ Ws,
                             float* __restrict__ s, int n) {
    int tid = threadIdx.x;
    int col = tid & 63;
    int node = blockIdx.x * 4 + (tid >> 6);
    float v = 0.f;
    if (node < n) v = X[node * 64 + col] * Ws[col];
    for (int off = 32; off; off >>= 1) v += __shfl_down(v, off);
    if (col == 0 && node < n) s[node] = v;
}

// ---------------------------------------------------------------------------
// Scalar SpMM (COO): v_out[row[e]] += val[e] * v_in[col[e]] * inv_norm
// inv_norm derived from previous iteration's sum-of-squares (norm_ptr),
// folding F.normalize into the gather (linearity). norm_ptr==null -> scale 1.
// ---------------------------------------------------------------------------
__global__ void spmm_scalar_kernel(const int* __restrict__ row,
                                   const int* __restrict__ col,
                                   const float* __restrict__ val,
                                   const float* __restrict__ v_in,
                                   float* __restrict__ v_out,
                                   const float* __restrict__ norm_ptr, int E) {
    int e = blockIdx.x * 256 + threadIdx.x;
    if (e >= E) return;
    float scale = 1.f;
    if (norm_ptr) {
        float ss = *norm_ptr;
        scale = 1.f / fmaxf(sqrtf(ss), 1e-12f);
    }
    atomicAdd(v_out + row[e], val[e] * v_in[col[e]] * scale);
}

// ---------------------------------------------------------------------------
// w = vn - TAU*sign(vn); store w; accumulate sum(w^2) into norm_slot.
// ---------------------------------------------------------------------------
__global__ void shrink_norm_kernel(const float* __restrict__ vn,
                                   float* __restrict__ w,
                                   float* __restrict__ norm_slot, int n) {
    int i = blockIdx.x * 256 + threadIdx.x;
    float sq = 0.f;
    if (i < n) {
        float x = vn[i];
        float sg = (x > 0.f) ? 1.f : ((x < 0.f) ? -1.f : 0.f);
        float ww = x - TAU * sg;
        w[i] = ww;
        sq = ww * ww;
    }
    for (int off = 32; off; off >>= 1) sq += __shfl_down(sq, off);
    __shared__ float sh[4];
    int lane = threadIdx.x & 63, wid = threadIdx.x >> 6;
    if (lane == 0) sh[wid] = sq;
    __syncthreads();
    if (threadIdx.x == 0)
        atomicAdd(norm_slot, sh[0] + sh[1] + sh[2] + sh[3]);
}

// ---------------------------------------------------------------------------
// out[i] = v[i] / max(sqrt(ss), 1e-12)
// ---------------------------------------------------------------------------
__global__ void finalize_kernel(const float* __restrict__ v,
                                const float* __restrict__ norm_ptr,
                                float* __restrict__ out, int n) {
    int i = blockIdx.x * 256 + threadIdx.x;
    if (i >= n) return;
    float inv = 1.f / fmaxf(sqrtf(*norm_ptr), 1e-12f);
    out[i] = v[i] * inv;
}

extern "C" void kernel_launch(void* const* d_in, const int* in_sizes, int n_in,
                              void* d_out, int out_size, void* d_ws, size_t ws_size,
                              hipStream_t stream) {
    const int* A_row = (const int*)d_in[0];
    const int* A_col = (const int*)d_in[1];
    const float* A_val = (const float*)d_in[2];
    const int* L_row = (const int*)d_in[3];
    const int* L_col = (const int*)d_in[4];
    const float* L_val = (const float*)d_in[5];
    const float* embed = (const float*)d_in[6];
    const float* W1 = (const float*)d_in[7];
    const float* W2 = (const float*)d_in[8];
    const float* Ws = (const float*)d_in[9];
    float* out = (float*)d_out;

    const int E = in_sizes[0];
    const int D = 64;
    const int N = in_sizes[6] / D;
    const int ITERS = 10;

    char* ws = (char*)d_ws;
    size_t feat_bytes = (size_t)N * D * sizeof(float);
    float* X = (float*)ws;                         // [N,64]
    float* AX = (float*)(ws + feat_bytes);         // [N,64]
    float* v_cur = (float*)(ws + 2 * feat_bytes);  // [N]
    float* v_new = v_cur + N;                      // [N]
    float* norms = v_new + N;                      // [16]

    // X = embed
    hipMemcpyAsync(X, embed, feat_bytes, hipMemcpyDeviceToDevice, stream);

    // Two residual GNN layers
    int spmm_blocks = (E * 16 + 255) / 256;
    int layer_blocks = (N + 15) / 16;
    for (int l = 0; l < 2; ++l) {
        hipMemsetAsync(AX, 0, feat_bytes, stream);
        spmm_feat_kernel<<<spmm_blocks, 256, 0, stream>>>(A_row, A_col, A_val, X, AX, E);
        layer_kernel<<<layer_blocks, 256, 0, stream>>>(AX, l ? W2 : W1, X, N);
    }

    // Scores
    score_kernel<<<(N + 3) / 4, 256, 0, stream>>>(X, Ws, v_cur, N);

    // Power iterations
    hipMemsetAsync(norms, 0, 16 * sizeof(float), stream);
    int e_blocks = (E + 255) / 256;
    int n_blocks = (N + 255) / 256;
    for (int it = 0; it < ITERS; ++it) {
        hipMemsetAsync(v_new, 0, (size_t)N * sizeof(float), stream);
        spmm_scalar_kernel<<<e_blocks, 256, 0, stream>>>(
            L_row, L_col, L_val, v_cur, v_new, it ? (norms + it - 1) : nullptr, E);
        shrink_norm_kernel<<<n_blocks, 256, 0, stream>>>(v_new, v_cur, norms + it, N);
    }
    finalize_kernel<<<n_blocks, 256, 0, stream>>>(v_cur, norms + ITERS - 1, out, N);
}

// Round 2
// 1849.994 us; speedup vs baseline: 2.3576x; 2.3576x over previous
//
#include <hip/hip_runtime.h>
#include <hip/hip_bf16.h>
#include <math.h>

#define TAU 0.5f

// ---------------------------------------------------------------------------
// CSR build: histogram -> single-block exclusive scan -> scatter.
// ---------------------------------------------------------------------------
__global__ void hist_kernel(const int* __restrict__ row, int* __restrict__ deg, int E) {
    int e = blockIdx.x * 256 + threadIdx.x;
    if (e < E) atomicAdd(&deg[row[e]], 1);
}

// Single block of 1024 threads: exclusive scan of deg[0..n) into row_ptr[0..n],
// duplicate into next[] (scatter cursor). row_ptr[n] = total.
__global__ void scan_kernel(const int* __restrict__ deg, int* __restrict__ row_ptr,
                            int* __restrict__ next, int n) {
    __shared__ int sums[1024];
    int t = threadIdx.x;
    int C = (n + 1023) >> 10;
    int s0 = t * C;
    int s1 = min(s0 + C, n);
    int local = 0;
    for (int i = s0; i < s1; ++i) local += deg[i];
    sums[t] = local;
    __syncthreads();
    for (int off = 1; off < 1024; off <<= 1) {
        int v = (t >= off) ? sums[t - off] : 0;
        __syncthreads();
        sums[t] += v;
        __syncthreads();
    }
    int run = (t == 0) ? 0 : sums[t - 1];
    for (int i = s0; i < s1; ++i) {
        int d = deg[i];
        row_ptr[i] = run;
        next[i] = run;
        run += d;
    }
    if (t == 0) row_ptr[n] = sums[1023];
}

__global__ void scatter_kernel(const int* __restrict__ row, const int* __restrict__ col,
                               const float* __restrict__ val, int* __restrict__ next,
                               int* __restrict__ col_s, float* __restrict__ val_s, int E) {
    int e = blockIdx.x * 256 + threadIdx.x;
    if (e >= E) return;
    int p = atomicAdd(&next[row[e]], 1);
    col_s[p] = col[e];
    val_s[p] = val[e];
}

// ---------------------------------------------------------------------------
// Feature SpMM (CSR): one wave per row, lane = feature. No atomics.
// ---------------------------------------------------------------------------
__global__ void spmm_feat_csr_kernel(const int* __restrict__ row_ptr,
                                     const int* __restrict__ col_s,
                                     const float* __restrict__ val_s,
                                     const float* __restrict__ X,
                                     float* __restrict__ AX, int n) {
    int wid = (blockIdx.x * 256 + threadIdx.x) >> 6;
    int lane = threadIdx.x & 63;
    if (wid >= n) return;
    int p = row_ptr[wid];
    int end = row_ptr[wid + 1];
    float acc0 = 0.f, acc1 = 0.f;
    for (; p + 2 <= end; p += 2) {
        int c0 = col_s[p];
        int c1 = col_s[p + 1];
        float v0 = val_s[p];
        float v1 = val_s[p + 1];
        acc0 += v0 * X[c0 * 64 + lane];
        acc1 += v1 * X[c1 * 64 + lane];
    }
    if (p < end) acc0 += val_s[p] * X[col_s[p] * 64 + lane];
    AX[wid * 64 + lane] = acc0 + acc1;
}

// ---------------------------------------------------------------------------
// X += relu(AX @ W^T).  W (64,64) row-major, staged transposed in LDS.
// 16 nodes per 256-thread block.
// ---------------------------------------------------------------------------
__global__ void layer_kernel(const float* __restrict__ AX,
                             const float* __restrict__ W,
                             float* __restrict__ X, int n) {
    __shared__ float Wt[64 * 65];
    __shared__ float AXs[16 * 64];
    int tid = threadIdx.x;
    for (int i = tid; i < 4096; i += 256) {
        int j = i >> 6, k = i & 63;
        Wt[k * 65 + j] = W[i];
    }
    int node0 = blockIdx.x * 16;
    for (int i = tid; i < 1024; i += 256) {
        int node = node0 + (i >> 6);
        AXs[i] = (node < n) ? AX[node * 64 + (i & 63)] : 0.f;
    }
    __syncthreads();
    int col = tid & 63;
    int nq = tid >> 6;  // 0..3
    float acc0 = 0.f, acc1 = 0.f, acc2 = 0.f, acc3 = 0.f;
    for (int k = 0; k < 64; ++k) {
        float w = Wt[k * 65 + col];
        acc0 += AXs[(nq + 0) * 64 + k] * w;
        acc1 += AXs[(nq + 4) * 64 + k] * w;
        acc2 += AXs[(nq + 8) * 64 + k] * w;
        acc3 += AXs[(nq + 12) * 64 + k] * w;
    }
    float accs[4] = {acc0, acc1, acc2, acc3};
#pragma unroll
    for (int j = 0; j < 4; ++j) {
        int node = node0 + nq + 4 * j;
        if (node < n) {
            int idx = node * 64 + col;
            X[idx] = X[idx] + fmaxf(accs[j], 0.f);
        }
    }
}

// ---------------------------------------------------------------------------
// s[i] = dot(X[i,:], Ws[0,:])  — wave-per-node shuffle reduction.
// ---------------------------------------------------------------------------
__global__ void score_kernel(const float* __restrict__ X,
                             const float* __restrict__ Ws,
                             float* __restrict__ s, int n) {
    int tid = threadIdx.x;
    int col = tid & 63;
    int node = blockIdx.x * 4 + (tid >> 6);
    float v = 0.f;
    if (node < n) v = X[node * 64 + col] * Ws[col];
    for (int off = 32; off; off >>= 1) v += __shfl_down(v, off);
    if (col == 0 && node < n) s[node] = v;
}

// ---------------------------------------------------------------------------
// Fused power iteration (CSR, thread per row, single writer):
//   s      = (L v_in) ; scale = prev inv-norm (folded normalize)
//   w      = s*scale - TAU*sign(s)        [sign(s*scale)==sign(s), scale>0]
//   v_out  = w ; norm_out += w^2
// ---------------------------------------------------------------------------
__global__ void power_iter_kernel(const int* __restrict__ row_ptr,
                                  const int* __restrict__ col_s,
                                  const float* __restrict__ val_s,
                                  const float* __restrict__ v_in,
                                  float* __restrict__ v_out,
                                  const float* __restrict__ norm_prev,
                                  float* __restrict__ norm_out, int n) {
    int i = blockIdx.x * 256 + threadIdx.x;
    float sq = 0.f;
    if (i < n) {
        int p = row_ptr[i];
        int end = row_ptr[i + 1];
        float s0 = 0.f, s1 = 0.f;
        for (; p + 2 <= end; p += 2) {
            s0 += val_s[p] * v_in[col_s[p]];
            s1 += val_s[p + 1] * v_in[col_s[p + 1]];
        }
        if (p < end) s0 += val_s[p] * v_in[col_s[p]];
        float s = s0 + s1;
        float scale = 1.f;
        if (norm_prev) scale = 1.f / fmaxf(sqrtf(*norm_prev), 1e-12f);
        float sg = (s > 0.f) ? 1.f : ((s < 0.f) ? -1.f : 0.f);
        float w = s * scale - TAU * sg;
        v_out[i] = w;
        sq = w * w;
    }
    for (int off = 32; off; off >>= 1) sq += __shfl_down(sq, off);
    __shared__ float sh[4];
    int lane = threadIdx.x & 63, wv = threadIdx.x >> 6;
    if (lane == 0) sh[wv] = sq;
    __syncthreads();
    if (threadIdx.x == 0) atomicAdd(norm_out, sh[0] + sh[1] + sh[2] + sh[3]);
}

// ---------------------------------------------------------------------------
// out[i] = v[i] / max(sqrt(ss), 1e-12)
// ---------------------------------------------------------------------------
__global__ void finalize_kernel(const float* __restrict__ v,
                                const float* __restrict__ norm_ptr,
                                float* __restrict__ out, int n) {
    int i = blockIdx.x * 256 + threadIdx.x;
    if (i >= n) return;
    float inv = 1.f / fmaxf(sqrtf(*norm_ptr), 1e-12f);
    out[i] = v[i] * inv;
}

extern "C" void kernel_launch(void* const* d_in, const int* in_sizes, int n_in,
                              void* d_out, int out_size, void* d_ws, size_t ws_size,
                              hipStream_t stream) {
    const int* A_row = (const int*)d_in[0];
    const int* A_col = (const int*)d_in[1];
    const float* A_val = (const float*)d_in[2];
    const int* L_row = (const int*)d_in[3];
    const int* L_col = (const int*)d_in[4];
    const float* L_val = (const float*)d_in[5];
    const float* embed = (const float*)d_in[6];
    const float* W1 = (const float*)d_in[7];
    const float* W2 = (const float*)d_in[8];
    const float* Ws = (const float*)d_in[9];
    float* out = (float*)d_out;

    const int E = in_sizes[0];
    const int D = 64;
    const int N = in_sizes[6] / D;
    const int ITERS = 10;

    // ---- workspace carve-up (all offsets 256B-aligned by construction) ----
    char* ws = (char*)d_ws;
    size_t off = 0;
    auto carve = [&](size_t bytes) {
        void* p = ws + off;
        off += (bytes + 255) & ~(size_t)255;
        return p;
    };
    float* X = (float*)carve((size_t)N * D * sizeof(float));       // 25.6 MB
    float* AX = (float*)carve((size_t)N * D * sizeof(float));      // 25.6 MB
    int* A_rp = (int*)carve((size_t)(N + 1) * sizeof(int));
    int* A_cs = (int*)carve((size_t)E * sizeof(int));
    float* A_vs = (float*)carve((size_t)E * sizeof(float));
    int* L_rp = (int*)carve((size_t)(N + 1) * sizeof(int));
    int* L_cs = (int*)carve((size_t)E * sizeof(int));
    float* L_vs = (float*)carve((size_t)E * sizeof(float));
    int* deg = (int*)carve((size_t)N * sizeof(int));
    int* nxt = (int*)carve((size_t)N * sizeof(int));
    float* v_cur = (float*)carve((size_t)N * sizeof(float));
    float* v_new = (float*)carve((size_t)N * sizeof(float));
    float* norms = (float*)carve(16 * sizeof(float));

    int e_blocks = (E + 255) / 256;
    int n_blocks = (N + 255) / 256;

    // ---- CSR build for A and L ----
    hipMemsetAsync(deg, 0, (size_t)N * sizeof(int), stream);
    hist_kernel<<<e_blocks, 256, 0, stream>>>(A_row, deg, E);
    scan_kernel<<<1, 1024, 0, stream>>>(deg, A_rp, nxt, N);
    scatter_kernel<<<e_blocks, 256, 0, stream>>>(A_row, A_col, A_val, nxt, A_cs, A_vs, E);

    hipMemsetAsync(deg, 0, (size_t)N * sizeof(int), stream);
    hist_kernel<<<e_blocks, 256, 0, stream>>>(L_row, deg, E);
    scan_kernel<<<1, 1024, 0, stream>>>(deg, L_rp, nxt, N);
    scatter_kernel<<<e_blocks, 256, 0, stream>>>(L_row, L_col, L_val, nxt, L_cs, L_vs, E);

    // ---- X = embed ----
    hipMemcpyAsync(X, embed, (size_t)N * D * sizeof(float),
                   hipMemcpyDeviceToDevice, stream);

    // ---- two residual GNN layers (no AX memset needed: single writer) ----
    int spmm_blocks = (N + 3) / 4;     // 4 waves (rows) per 256-thread block
    int layer_blocks = (N + 15) / 16;
    for (int l = 0; l < 2; ++l) {
        spmm_feat_csr_kernel<<<spmm_blocks, 256, 0, stream>>>(A_rp, A_cs, A_vs, X, AX, N);
        layer_kernel<<<layer_blocks, 256, 0, stream>>>(AX, l ? W2 : W1, X, N);
    }

    // ---- scores ----
    score_kernel<<<(N + 3) / 4, 256, 0, stream>>>(X, Ws, v_cur, N);

    // ---- power iterations (fused spmm+shrink+norm; normalize folded) ----
    hipMemsetAsync(norms, 0, 16 * sizeof(float), stream);
    float* cur = v_cur;
    float* nxt_v = v_new;
    for (int it = 0; it < ITERS; ++it) {
        power_iter_kernel<<<n_blocks, 256, 0, stream>>>(
            L_rp, L_cs, L_vs, cur, nxt_v,
            it ? (norms + it - 1) : nullptr, norms + it, N);
        float* t = cur; cur = nxt_v; nxt_v = t;
    }
    finalize_kernel<<<n_blocks, 256, 0, stream>>>(cur, norms + ITERS - 1, out, N);
}